// Round 1
// baseline (56.252 us; speedup 1.0000x reference)
//
#include <hip/hip_runtime.h>
#include <math.h>

// Problem constants (fixed by reference setup_inputs): x [2,3,512,512] f32.
#define B_ 2
#define C_ 3
#define BC 6
#define H_ 512
#define W_ 512
#define HW (H_ * W_)
#define EPS 1e-6f
#define EXPM05 0.60653065971263342f  // exp(-0.5)

#define BX 16
#define BY 16
#define HALO 4
#define TS (BX + 2 * HALO)   // 24
#define LSTRIDE (TS + 1)     // 25 (bank-conflict padding)

__global__ __launch_bounds__(256) void texmart_kernel(const float* __restrict__ x,
                                                      float* __restrict__ out) {
    __shared__ float xs[TS][LSTRIDE];
    __shared__ float pl[TS][LSTRIDE];

    const int tx = threadIdx.x, ty = threadIdx.y;
    const int bx = blockIdx.x * BX, by = blockIdx.y * BY;
    const int plane = blockIdx.z;                // b*C + c
    const float* __restrict__ xp = x + (size_t)plane * HW;

    // --- Stage tile + halo into LDS, precompute p*log(p+EPS). Zero padding
    // matches the reference's F.unfold-style zero pad (plog of 0 is 0).
    const int tid = ty * BX + tx;
    for (int idx = tid; idx < TS * TS; idx += BX * BY) {
        const int ly = idx / TS, lx = idx % TS;
        const int gy = by - HALO + ly, gx = bx - HALO + lx;
        float v = 0.0f;
        if (gy >= 0 && gy < H_ && gx >= 0 && gx < W_) v = xp[gy * W_ + gx];
        xs[ly][lx] = v;
        pl[ly][lx] = v * __logf(v + EPS);
    }
    __syncthreads();

    const int cy = ty + HALO, cx = tx + HALO;

    // --- Pass 1: ring-wise sums (Chebyshev rings 0..4), then prefix over rings.
    float s1[5] = {0, 0, 0, 0, 0};
    float s2[5] = {0, 0, 0, 0, 0};
    float sl[5] = {0, 0, 0, 0, 0};
#pragma unroll
    for (int di = -HALO; di <= HALO; ++di) {
#pragma unroll
        for (int dj = -HALO; dj <= HALO; ++dj) {
            const int ai = di < 0 ? -di : di;
            const int aj = dj < 0 ? -dj : dj;
            const int r = ai > aj ? ai : aj;   // constant after unroll
            const float p = xs[cy + di][cx + dj];
            const float q = pl[cy + di][cx + dj];
            s1[r] += p;
            s2[r] = __fmaf_rn(p, p, s2[r]);
            sl[r] += q;
        }
    }

    float cS1[5], cS2[5], cSL[5];
    {
        float a = 0.f, b = 0.f, c = 0.f;
#pragma unroll
        for (int r = 0; r < 5; ++r) {
            a += s1[r]; b += s2[r]; c += sl[r];
            cS1[r] = a; cS2[r] = b; cSL[r] = c;
        }
    }

    float mean[5];
#pragma unroll
    for (int R = 1; R <= 4; ++R) {
        const float K = (float)((2 * R + 1) * (2 * R + 1));
        mean[R] = cS1[R] / K;
    }

    // --- Pass 2: homogeneity sums Σ|p - mean_R| (mean differs per window).
    float sa[5] = {0, 0, 0, 0, 0};
#pragma unroll
    for (int di = -HALO; di <= HALO; ++di) {
#pragma unroll
        for (int dj = -HALO; dj <= HALO; ++dj) {
            const int ai = di < 0 ? -di : di;
            const int aj = dj < 0 ? -dj : dj;
            const int r = ai > aj ? ai : aj;   // constant after unroll
            const float p = xs[cy + di][cx + dj];
#pragma unroll
            for (int R = 1; R <= 4; ++R) {
                if (R >= r) sa[R] += fabsf(p - mean[R]);
            }
        }
    }

    // --- Finalize + write. Output channel layout: c*16 + (window*4 + feature).
    const int gy = by + ty, gx = bx + tx;
    float* __restrict__ op = out + (size_t)plane * 16 * HW + (size_t)gy * W_ + gx;
#pragma unroll
    for (int R = 1; R <= 4; ++R) {
        const float K = (float)((2 * R + 1) * (2 * R + 1));
        const float m = mean[R];
        float S2c = cS2[R] - cS1[R] * m;   // Σ(p-mean)²
        if (S2c < 0.f) S2c = 0.f;
        const float varK = S2c / K;                        // mean((p-mean)²)
        const float sd = sqrtf(S2c / (K - 1.f)) + EPS;     // torch-style ddof=1 std + EPS
        const float contrast = varK / (sd * sd);
        const float energy = cS2[R] / K;
        const float entropy = -cSL[R] / K;
        const float homog = 1.f / (1.f + sa[R] / K);

        float* __restrict__ o = op + (size_t)(R - 1) * 4 * HW;
        o[0 * HW] = (contrast + EPS) * EXPM05;   // exp(log(f+EPS) - 0.5) = (f+EPS)e^-0.5
        o[1 * HW] = (energy   + EPS) * EXPM05;
        o[2 * HW] = (entropy  + EPS) * EXPM05;
        o[3 * HW] = (homog    + EPS) * EXPM05;
    }
}

extern "C" void kernel_launch(void* const* d_in, const int* in_sizes, int n_in,
                              void* d_out, int out_size, void* d_ws, size_t ws_size,
                              hipStream_t stream) {
    const float* x = (const float*)d_in[0];
    float* out = (float*)d_out;
    dim3 block(BX, BY, 1);
    dim3 grid(W_ / BX, H_ / BY, BC);
    texmart_kernel<<<grid, block, 0, stream>>>(x, out);
}